// Round 2
// baseline (4058.769 us; speedup 1.0000x reference)
//
#include <hip/hip_runtime.h>
#include <math.h>

#define H 24
#define H4 6   // H/4

// scalar f32 atomic add, no return (global_atomic_add_f32, gfx90a+)
__device__ __forceinline__ void atomic_add_f32(float* addr, float v) {
    asm volatile("global_atomic_add_f32 %0, %1, off" :: "v"(addr), "v"(v) : "memory");
}

__device__ __forceinline__ float sigmoidf_(float v) {
    return 1.0f / (1.0f + __expf(-v));
}

__global__ __launch_bounds__(256) void deg_kernel(const int* __restrict__ dst,
                                                  unsigned* __restrict__ deg, int E) {
    int e = blockIdx.x * blockDim.x + threadIdx.x;
    if (e < E) atomicAdd(&deg[dst[e]], 1u);
}

__global__ __launch_bounds__(256) void node_kernel(
    const float* __restrict__ x, const float* __restrict__ h0, const float* __restrict__ c0,
    const float* __restrict__ w_ih, const float* __restrict__ w_hh,
    const float* __restrict__ b_ih, const float* __restrict__ b_hh,
    const float* __restrict__ gcn_w, const unsigned* __restrict__ deg,
    float* __restrict__ out_h, float* __restrict__ out_c,
    float* __restrict__ xw, float* __restrict__ dinv, float* __restrict__ agg, int N)
{
    int n = blockIdx.x * blockDim.x + threadIdx.x;
    if (n >= N) return;

    float hp[H];
    {
        const float4* p = (const float4*)(h0 + (size_t)n * H);
        #pragma unroll
        for (int q = 0; q < H4; q++) {
            float4 v = p[q];
            hp[4*q+0] = v.x; hp[4*q+1] = v.y; hp[4*q+2] = v.z; hp[4*q+3] = v.w;
        }
    }
    float cp[H];
    {
        const float4* p = (const float4*)(c0 + (size_t)n * H);
        #pragma unroll
        for (int q = 0; q < H4; q++) {
            float4 v = p[q];
            cp[4*q+0] = v.x; cp[4*q+1] = v.y; cp[4*q+2] = v.z; cp[4*q+3] = v.w;
        }
    }
    float xv = x[n];

    float hv[H], cvv[H];
    #pragma unroll
    for (int k = 0; k < H; k++) {
        // gates in torch order: i, f, g, o  (rows k, k+24, k+48, k+72 of the 4H x H matrices)
        float gi = b_ih[k]      + b_hh[k]      + xv * w_ih[k];
        float gf = b_ih[k + 24] + b_hh[k + 24] + xv * w_ih[k + 24];
        float gg = b_ih[k + 48] + b_hh[k + 48] + xv * w_ih[k + 48];
        float go = b_ih[k + 72] + b_hh[k + 72] + xv * w_ih[k + 72];
        #pragma unroll
        for (int j = 0; j < H; j++) {
            float hj = hp[j];
            gi = fmaf(hj, w_hh[(k)      * H + j], gi);
            gf = fmaf(hj, w_hh[(k + 24) * H + j], gf);
            gg = fmaf(hj, w_hh[(k + 48) * H + j], gg);
            go = fmaf(hj, w_hh[(k + 72) * H + j], go);
        }
        gi = sigmoidf_(gi);
        gf = sigmoidf_(gf);
        go = sigmoidf_(go);
        gg = tanhf(gg);
        float c_ = fmaf(gf, cp[k], gi * gg);
        float h_ = go * tanhf(c_);
        cvv[k] = c_;
        hv[k]  = h_;
    }

    // GCN input transform: xw[n,j] = sum_k h[k] * gcn_w[j,k]
    float di = rsqrtf((float)deg[n] + 1.0f);
    dinv[n] = di;
    float di2 = di * di;

    float xwv[H];
    #pragma unroll
    for (int j = 0; j < H; j++) {
        float acc = 0.0f;
        #pragma unroll
        for (int k = 0; k < H; k++) acc = fmaf(hv[k], gcn_w[j * H + k], acc);
        xwv[j] = acc;
    }

    float4* oh = (float4*)(out_h + (size_t)n * H);
    float4* oc = (float4*)(out_c + (size_t)n * H);
    float4* ox = (float4*)(xw    + (size_t)n * H);
    float4* oa = (float4*)(agg   + (size_t)n * H);
    #pragma unroll
    for (int q = 0; q < H4; q++) {
        oh[q] = make_float4(hv[4*q+0], hv[4*q+1], hv[4*q+2], hv[4*q+3]);
        oc[q] = make_float4(cvv[4*q+0], cvv[4*q+1], cvv[4*q+2], cvv[4*q+3]);
        ox[q] = make_float4(xwv[4*q+0], xwv[4*q+1], xwv[4*q+2], xwv[4*q+3]);
        // self-loop contribution initializes agg (edge kernel atomically adds on top)
        oa[q] = make_float4(xwv[4*q+0]*di2, xwv[4*q+1]*di2, xwv[4*q+2]*di2, xwv[4*q+3]*di2);
    }
}

__global__ __launch_bounds__(256) void edge_kernel(
    const int* __restrict__ src, const int* __restrict__ dst,
    const float* __restrict__ xw, const float* __restrict__ dinv,
    float* __restrict__ agg, int E)
{
    int e = blockIdx.x * blockDim.x + threadIdx.x;
    if (e >= E) return;
    int s = src[e], d = dst[e];
    float w = dinv[s] * dinv[d];
    const float4* xs = (const float4*)(xw + (size_t)s * H);
    float* ad = agg + (size_t)d * H;
    #pragma unroll
    for (int q = 0; q < H4; q++) {
        float4 v = xs[q];
        atomic_add_f32(ad + 4*q + 0, v.x * w);
        atomic_add_f32(ad + 4*q + 1, v.y * w);
        atomic_add_f32(ad + 4*q + 2, v.z * w);
        atomic_add_f32(ad + 4*q + 3, v.w * w);
    }
}

__global__ __launch_bounds__(256) void final_kernel(
    const float* __restrict__ x, const float* __restrict__ agg,
    const float* __restrict__ gcn_b, const float* __restrict__ lin_w,
    const float* __restrict__ lin_b, float* __restrict__ out, int N)
{
    int n = blockIdx.x * blockDim.x + threadIdx.x;
    if (n >= N) return;
    const float4* a4 = (const float4*)(agg + (size_t)n * H);
    float acc = lin_b[0];
    #pragma unroll
    for (int q = 0; q < H4; q++) {
        float4 a = a4[q];
        acc = fmaf(a.x + gcn_b[4*q+0], lin_w[4*q+0], acc);
        acc = fmaf(a.y + gcn_b[4*q+1], lin_w[4*q+1], acc);
        acc = fmaf(a.z + gcn_b[4*q+2], lin_w[4*q+2], acc);
        acc = fmaf(a.w + gcn_b[4*q+3], lin_w[4*q+3], acc);
    }
    out[n] = x[n] * acc;
}

extern "C" void kernel_launch(void* const* d_in, const int* in_sizes, int n_in,
                              void* d_out, int out_size, void* d_ws, size_t ws_size,
                              hipStream_t stream) {
    const float* x     = (const float*)d_in[0];
    const float* h0    = (const float*)d_in[1];
    const float* c0    = (const float*)d_in[2];
    const int*   ei    = (const int*)d_in[3];
    const float* w_ih  = (const float*)d_in[4];
    const float* w_hh  = (const float*)d_in[5];
    const float* b_ih  = (const float*)d_in[6];
    const float* b_hh  = (const float*)d_in[7];
    const float* gcn_w = (const float*)d_in[8];
    const float* gcn_b = (const float*)d_in[9];
    const float* lin_w = (const float*)d_in[10];
    const float* lin_b = (const float*)d_in[11];

    const int N = in_sizes[0];
    const int E = in_sizes[3] / 2;
    const int* src = ei;
    const int* dst = ei + E;

    float* out_gate = (float*)d_out;                 // [N]
    float* out_h    = out_gate + N;                  // [N*H]
    float* out_c    = out_h + (size_t)N * H;         // [N*H]

    float*    xw   = (float*)d_ws;                   // N*H
    float*    agg  = xw + (size_t)N * H;             // N*H
    float*    dinv = agg + (size_t)N * H;            // N
    unsigned* deg  = (unsigned*)(dinv + N);          // N

    hipMemsetAsync(deg, 0, (size_t)N * sizeof(unsigned), stream);

    deg_kernel <<<(E + 255) / 256, 256, 0, stream>>>(dst, deg, E);
    node_kernel<<<(N + 255) / 256, 256, 0, stream>>>(x, h0, c0, w_ih, w_hh, b_ih, b_hh,
                                                     gcn_w, deg, out_h, out_c, xw, dinv, agg, N);
    edge_kernel<<<(E + 255) / 256, 256, 0, stream>>>(src, dst, xw, dinv, agg, E);
    final_kernel<<<(N + 255) / 256, 256, 0, stream>>>(x, agg, gcn_b, lin_w, lin_b, out_gate, N);
}

// Round 3
// 382.780 us; speedup vs baseline: 10.6034x; 10.6034x over previous
//
#include <hip/hip_runtime.h>
#include <math.h>

#define H 24
#define H4 6   // H/4

// scalar f32 atomic add, no return (global_atomic_add_f32, gfx90a+)
__device__ __forceinline__ void atomic_add_f32(float* addr, float v) {
    asm volatile("global_atomic_add_f32 %0, %1, off" :: "v"(addr), "v"(v) : "memory");
}

__device__ __forceinline__ float sigmoidf_(float v) {
    return 1.0f / (1.0f + __expf(-v));
}

__global__ __launch_bounds__(256) void deg_kernel(const int* __restrict__ dst,
                                                  unsigned* __restrict__ deg, int E) {
    int e = blockIdx.x * blockDim.x + threadIdx.x;
    if (e < E) atomicAdd(&deg[dst[e]], 1u);   // no-return form expected (m20)
}

__global__ __launch_bounds__(256) void node_kernel(
    const float* __restrict__ x, const float* __restrict__ h0, const float* __restrict__ c0,
    const float* __restrict__ w_ih, const float* __restrict__ w_hh,
    const float* __restrict__ b_ih, const float* __restrict__ b_hh,
    const float* __restrict__ gcn_w, const float* __restrict__ lin_w,
    const unsigned* __restrict__ deg,
    float* __restrict__ out_h, float* __restrict__ out_c,
    float* __restrict__ y, float* __restrict__ z, float* __restrict__ dinv, int N)
{
    int n = blockIdx.x * blockDim.x + threadIdx.x;
    if (n >= N) return;

    float hp[H];
    {
        const float4* p = (const float4*)(h0 + (size_t)n * H);
        #pragma unroll
        for (int q = 0; q < H4; q++) {
            float4 v = p[q];
            hp[4*q+0] = v.x; hp[4*q+1] = v.y; hp[4*q+2] = v.z; hp[4*q+3] = v.w;
        }
    }
    float cp[H];
    {
        const float4* p = (const float4*)(c0 + (size_t)n * H);
        #pragma unroll
        for (int q = 0; q < H4; q++) {
            float4 v = p[q];
            cp[4*q+0] = v.x; cp[4*q+1] = v.y; cp[4*q+2] = v.z; cp[4*q+3] = v.w;
        }
    }
    float xv = x[n];

    float hv[H], cvv[H];
    #pragma unroll
    for (int k = 0; k < H; k++) {
        // gates in torch order: i, f, g, o (rows k, k+24, k+48, k+72)
        float gi = b_ih[k]      + b_hh[k]      + xv * w_ih[k];
        float gf = b_ih[k + 24] + b_hh[k + 24] + xv * w_ih[k + 24];
        float gg = b_ih[k + 48] + b_hh[k + 48] + xv * w_ih[k + 48];
        float go = b_ih[k + 72] + b_hh[k + 72] + xv * w_ih[k + 72];
        #pragma unroll
        for (int j = 0; j < H; j++) {
            float hj = hp[j];
            gi = fmaf(hj, w_hh[(k)      * H + j], gi);
            gf = fmaf(hj, w_hh[(k + 24) * H + j], gf);
            gg = fmaf(hj, w_hh[(k + 48) * H + j], gg);
            go = fmaf(hj, w_hh[(k + 72) * H + j], go);
        }
        gi = sigmoidf_(gi);
        gf = sigmoidf_(gf);
        go = sigmoidf_(go);
        gg = tanhf(gg);
        float c_ = fmaf(gf, cp[k], gi * gg);
        float h_ = go * tanhf(c_);
        cvv[k] = c_;
        hv[k]  = h_;
    }

    // y[n] = (h @ gcn_w.T) . lin_w   (collapse GCN transform + Linear into a scalar)
    // y = sum_j lin_w[j] * sum_k h[k]*gcn_w[j,k] = sum_k h[k] * (sum_j lin_w[j]*gcn_w[j,k])
    // keep the j-then-k order identical to reference shape for accuracy; either is fine.
    float yv = 0.0f;
    #pragma unroll
    for (int j = 0; j < H; j++) {
        float acc = 0.0f;
        #pragma unroll
        for (int k = 0; k < H; k++) acc = fmaf(hv[k], gcn_w[j * H + k], acc);
        yv = fmaf(acc, lin_w[j], yv);
    }

    float di = rsqrtf((float)deg[n] + 1.0f);
    dinv[n] = di;
    y[n] = yv;
    z[n] = di * yv;

    float4* oh = (float4*)(out_h + (size_t)n * H);
    float4* oc = (float4*)(out_c + (size_t)n * H);
    #pragma unroll
    for (int q = 0; q < H4; q++) {
        oh[q] = make_float4(hv[4*q+0], hv[4*q+1], hv[4*q+2], hv[4*q+3]);
        oc[q] = make_float4(cvv[4*q+0], cvv[4*q+1], cvv[4*q+2], cvv[4*q+3]);
    }
}

__global__ __launch_bounds__(256) void edge_kernel(
    const int* __restrict__ src, const int* __restrict__ dst,
    const float* __restrict__ z, float* __restrict__ acc, int E)
{
    int e = blockIdx.x * blockDim.x + threadIdx.x;
    if (e >= E) return;
    int s = src[e], d = dst[e];
    atomic_add_f32(acc + d, z[s]);   // one atomic per edge
}

__global__ __launch_bounds__(256) void final_kernel(
    const float* __restrict__ x, const float* __restrict__ acc,
    const float* __restrict__ y, const float* __restrict__ dinv,
    const float* __restrict__ gcn_b, const float* __restrict__ lin_w,
    const float* __restrict__ lin_b, float* __restrict__ out, int N)
{
    int n = blockIdx.x * blockDim.x + threadIdx.x;
    if (n >= N) return;
    // constant term: gcn_b . lin_w + lin_b  (broadcast reads, L1-cached)
    float cb = lin_b[0];
    #pragma unroll
    for (int j = 0; j < H; j++) cb = fmaf(gcn_b[j], lin_w[j], cb);
    float di = dinv[n];
    float s  = di * acc[n] + di * di * y[n] + cb;
    out[n] = x[n] * s;
}

extern "C" void kernel_launch(void* const* d_in, const int* in_sizes, int n_in,
                              void* d_out, int out_size, void* d_ws, size_t ws_size,
                              hipStream_t stream) {
    const float* x     = (const float*)d_in[0];
    const float* h0    = (const float*)d_in[1];
    const float* c0    = (const float*)d_in[2];
    const int*   ei    = (const int*)d_in[3];
    const float* w_ih  = (const float*)d_in[4];
    const float* w_hh  = (const float*)d_in[5];
    const float* b_ih  = (const float*)d_in[6];
    const float* b_hh  = (const float*)d_in[7];
    const float* gcn_w = (const float*)d_in[8];
    const float* gcn_b = (const float*)d_in[9];
    const float* lin_w = (const float*)d_in[10];
    const float* lin_b = (const float*)d_in[11];

    const int N = in_sizes[0];
    const int E = in_sizes[3] / 2;
    const int* src = ei;
    const int* dst = ei + E;

    float* out_gate = (float*)d_out;                 // [N]
    float* out_h    = out_gate + N;                  // [N*H]
    float* out_c    = out_h + (size_t)N * H;         // [N*H]

    float*    y    = (float*)d_ws;                   // N
    float*    zv   = y + N;                          // N
    float*    dinv = zv + N;                         // N
    float*    acc  = dinv + N;                       // N  (zeroed)
    unsigned* deg  = (unsigned*)(acc + N);           // N  (zeroed)

    // acc and deg are adjacent: one memset covers both
    hipMemsetAsync(acc, 0, (size_t)2 * N * sizeof(float), stream);

    deg_kernel <<<(E + 255) / 256, 256, 0, stream>>>(dst, deg, E);
    node_kernel<<<(N + 255) / 256, 256, 0, stream>>>(x, h0, c0, w_ih, w_hh, b_ih, b_hh,
                                                     gcn_w, lin_w, deg, out_h, out_c,
                                                     y, zv, dinv, N);
    edge_kernel<<<(E + 255) / 256, 256, 0, stream>>>(src, dst, zv, acc, E);
    final_kernel<<<(N + 255) / 256, 256, 0, stream>>>(x, acc, y, dinv, gcn_b, lin_w,
                                                      lin_b, out_gate, N);
}

// Round 4
// 213.497 us; speedup vs baseline: 19.0109x; 1.7929x over previous
//
#include <hip/hip_runtime.h>
#include <math.h>

#define H 24
#define H4 6        // H/4
#define B0 4096     // dst nodes per bucket (LDS bins)
#define B0_SHIFT 12
#define MAXNB 64    // >= NB = ceil(N/B0) = 49
#define P 6         // partial copies per bucket (blocks per bucket)
#define K1_EPB 4096 // edges per scatter block

__device__ __forceinline__ float sigmoidf_(float v) {
    return 1.0f / (1.0f + __expf(-v));
}
// tanh via exp2-backed __expf: exact at saturation, ~1e-6 rel error
__device__ __forceinline__ float tanhf_(float v) {
    return 1.0f - 2.0f / (__expf(2.0f * v) + 1.0f);
}

// ---- K0: bucket sizes (LDS 49-bin histogram, ~25K global atomics total) ----
__global__ __launch_bounds__(256) void count_kernel(const int* __restrict__ dst,
                                                    unsigned* __restrict__ sizes,
                                                    int E, int NB) {
    __shared__ unsigned cnt[MAXNB];
    for (int i = threadIdx.x; i < NB; i += 256) cnt[i] = 0;
    __syncthreads();
    for (int e = blockIdx.x * 256 + threadIdx.x; e < E; e += gridDim.x * 256)
        atomicAdd(&cnt[((unsigned)dst[e]) >> B0_SHIFT], 1u);
    __syncthreads();
    for (int i = threadIdx.x; i < NB; i += 256)
        if (cnt[i]) atomicAdd(&sizes[i], cnt[i]);
}

// ---- K0b: exclusive prefix over NB bucket sizes ----
__global__ void prefix_kernel(const unsigned* __restrict__ sizes,
                              unsigned* __restrict__ bases,
                              unsigned* __restrict__ cursors, int NB) {
    if (threadIdx.x == 0 && blockIdx.x == 0) {
        unsigned b = 0;
        for (int i = 0; i < NB; i++) { bases[i] = b; cursors[i] = b; b += sizes[i]; }
    }
}

// ---- K1: scatter edges into bucket regions (block-aggregated reservation) ----
__global__ __launch_bounds__(256) void scatter_kernel(
    const int* __restrict__ src, const int* __restrict__ dst,
    unsigned* __restrict__ cursors, unsigned* __restrict__ psrc,
    unsigned short* __restrict__ pdst, int E, int NB)
{
    __shared__ unsigned cnt[MAXNB];
    __shared__ unsigned base[MAXNB];
    int start = blockIdx.x * K1_EPB;
    int end   = start + K1_EPB; if (end > E) end = E;
    for (int i = threadIdx.x; i < NB; i += 256) cnt[i] = 0;
    __syncthreads();
    for (int e = start + threadIdx.x; e < end; e += 256)
        atomicAdd(&cnt[((unsigned)dst[e]) >> B0_SHIFT], 1u);
    __syncthreads();
    for (int i = threadIdx.x; i < NB; i += 256) {
        unsigned c = cnt[i];
        base[i] = c ? atomicAdd(&cursors[i], c) : 0u;  // ~49 returning atomics/block
        cnt[i] = 0;
    }
    __syncthreads();
    for (int e = start + threadIdx.x; e < end; e += 256) {
        unsigned d = (unsigned)dst[e];
        unsigned b = d >> B0_SHIFT;
        unsigned slot = atomicAdd(&cnt[b], 1u);        // LDS returning atomic
        unsigned idx  = base[b] + slot;
        psrc[idx] = (unsigned)src[e];
        pdst[idx] = (unsigned short)(d & (B0 - 1));
    }
}

// ---- K2: per-bucket LDS degree histogram -> P partial copies (non-atomic writes) ----
__global__ __launch_bounds__(256) void deghist_kernel(
    const unsigned short* __restrict__ pdst,
    const unsigned* __restrict__ sizes, const unsigned* __restrict__ bases,
    unsigned* __restrict__ degp, int NB, int NPAD)
{
    __shared__ unsigned h[B0];
    int b = blockIdx.x % NB, p = blockIdx.x / NB;
    for (int i = threadIdx.x; i < B0; i += 256) h[i] = 0;
    __syncthreads();
    unsigned sz = sizes[b], base = bases[b];
    unsigned chunk = (sz + P - 1) / P;
    unsigned s0 = p * chunk;
    unsigned s1 = s0 + chunk; if (s1 > sz) s1 = sz;
    for (unsigned i = s0 + threadIdx.x; i < s1; i += 256)
        atomicAdd(&h[pdst[base + i]], 1u);
    __syncthreads();
    unsigned* out = degp + (size_t)p * NPAD + (size_t)b * B0;
    for (int i = threadIdx.x; i < B0; i += 256) out[i] = h[i];
}

// ---- node: LSTM + y = (h@gcn_w^T).lin_w, dinv from summed deg partials ----
__global__ __launch_bounds__(256) void node_kernel(
    const float* __restrict__ x, const float* __restrict__ h0, const float* __restrict__ c0,
    const float* __restrict__ w_ih, const float* __restrict__ w_hh,
    const float* __restrict__ b_ih, const float* __restrict__ b_hh,
    const float* __restrict__ gcn_w, const float* __restrict__ lin_w,
    const unsigned* __restrict__ degp, int NPAD,
    float* __restrict__ out_h, float* __restrict__ out_c,
    float* __restrict__ y, float* __restrict__ z, float* __restrict__ dinv, int N)
{
    int n = blockIdx.x * blockDim.x + threadIdx.x;
    if (n >= N) return;

    float hp[H];
    {
        const float4* p4 = (const float4*)(h0 + (size_t)n * H);
        #pragma unroll
        for (int q = 0; q < H4; q++) {
            float4 v = p4[q];
            hp[4*q+0] = v.x; hp[4*q+1] = v.y; hp[4*q+2] = v.z; hp[4*q+3] = v.w;
        }
    }
    float cp[H];
    {
        const float4* p4 = (const float4*)(c0 + (size_t)n * H);
        #pragma unroll
        for (int q = 0; q < H4; q++) {
            float4 v = p4[q];
            cp[4*q+0] = v.x; cp[4*q+1] = v.y; cp[4*q+2] = v.z; cp[4*q+3] = v.w;
        }
    }
    float xv = x[n];

    float hv[H], cvv[H];
    #pragma unroll
    for (int k = 0; k < H; k++) {
        float gi = b_ih[k]      + b_hh[k]      + xv * w_ih[k];
        float gf = b_ih[k + 24] + b_hh[k + 24] + xv * w_ih[k + 24];
        float gg = b_ih[k + 48] + b_hh[k + 48] + xv * w_ih[k + 48];
        float go = b_ih[k + 72] + b_hh[k + 72] + xv * w_ih[k + 72];
        #pragma unroll
        for (int j = 0; j < H; j++) {
            float hj = hp[j];
            gi = fmaf(hj, w_hh[(k)      * H + j], gi);
            gf = fmaf(hj, w_hh[(k + 24) * H + j], gf);
            gg = fmaf(hj, w_hh[(k + 48) * H + j], gg);
            go = fmaf(hj, w_hh[(k + 72) * H + j], go);
        }
        gi = sigmoidf_(gi);
        gf = sigmoidf_(gf);
        go = sigmoidf_(go);
        gg = tanhf_(gg);
        float c_ = fmaf(gf, cp[k], gi * gg);
        float h_ = go * tanhf_(c_);
        cvv[k] = c_;
        hv[k]  = h_;
    }

    float yv = 0.0f;
    #pragma unroll
    for (int j = 0; j < H; j++) {
        float acc = 0.0f;
        #pragma unroll
        for (int k = 0; k < H; k++) acc = fmaf(hv[k], gcn_w[j * H + k], acc);
        yv = fmaf(acc, lin_w[j], yv);
    }

    unsigned dg = 0;
    #pragma unroll
    for (int p = 0; p < P; p++) dg += degp[(size_t)p * NPAD + n];
    float di = rsqrtf((float)dg + 1.0f);
    dinv[n] = di;
    y[n] = yv;
    z[n] = di * yv;

    float4* oh = (float4*)(out_h + (size_t)n * H);
    float4* oc = (float4*)(out_c + (size_t)n * H);
    #pragma unroll
    for (int q = 0; q < H4; q++) {
        oh[q] = make_float4(hv[4*q+0], hv[4*q+1], hv[4*q+2], hv[4*q+3]);
        oc[q] = make_float4(cvv[4*q+0], cvv[4*q+1], cvv[4*q+2], cvv[4*q+3]);
    }
}

// ---- K5: per-bucket LDS f32 accumulation of z[src] (ds_add_f32) ----
__global__ __launch_bounds__(256) void acchist_kernel(
    const unsigned* __restrict__ psrc, const unsigned short* __restrict__ pdst,
    const unsigned* __restrict__ sizes, const unsigned* __restrict__ bases,
    const float* __restrict__ z, float* __restrict__ accp, int NB, int NPAD)
{
    __shared__ float h[B0];
    int b = blockIdx.x % NB, p = blockIdx.x / NB;
    for (int i = threadIdx.x; i < B0; i += 256) h[i] = 0.0f;
    __syncthreads();
    unsigned sz = sizes[b], base = bases[b];
    unsigned chunk = (sz + P - 1) / P;
    unsigned s0 = p * chunk;
    unsigned s1 = s0 + chunk; if (s1 > sz) s1 = sz;
    for (unsigned i = s0 + threadIdx.x; i < s1; i += 256) {
        unsigned idx = base + i;
        atomicAdd(&h[pdst[idx]], z[psrc[idx]]);
    }
    __syncthreads();
    float* out = accp + (size_t)p * NPAD + (size_t)b * B0;
    for (int i = threadIdx.x; i < B0; i += 256) out[i] = h[i];
}

// ---- final: sum acc partials, apply norm + bias + gate ----
__global__ __launch_bounds__(256) void final_kernel(
    const float* __restrict__ x, const float* __restrict__ accp, int NPAD,
    const float* __restrict__ y, const float* __restrict__ dinv,
    const float* __restrict__ gcn_b, const float* __restrict__ lin_w,
    const float* __restrict__ lin_b, float* __restrict__ out, int N)
{
    int n = blockIdx.x * blockDim.x + threadIdx.x;
    if (n >= N) return;
    float cb = lin_b[0];
    #pragma unroll
    for (int j = 0; j < H; j++) cb = fmaf(gcn_b[j], lin_w[j], cb);
    float a = 0.0f;
    #pragma unroll
    for (int p = 0; p < P; p++) a += accp[(size_t)p * NPAD + n];
    float di = dinv[n];
    float s  = di * a + di * di * y[n] + cb;
    out[n] = x[n] * s;
}

extern "C" void kernel_launch(void* const* d_in, const int* in_sizes, int n_in,
                              void* d_out, int out_size, void* d_ws, size_t ws_size,
                              hipStream_t stream) {
    const float* x     = (const float*)d_in[0];
    const float* h0    = (const float*)d_in[1];
    const float* c0    = (const float*)d_in[2];
    const int*   ei    = (const int*)d_in[3];
    const float* w_ih  = (const float*)d_in[4];
    const float* w_hh  = (const float*)d_in[5];
    const float* b_ih  = (const float*)d_in[6];
    const float* b_hh  = (const float*)d_in[7];
    const float* gcn_w = (const float*)d_in[8];
    const float* gcn_b = (const float*)d_in[9];
    const float* lin_w = (const float*)d_in[10];
    const float* lin_b = (const float*)d_in[11];

    const int N = in_sizes[0];
    const int E = in_sizes[3] / 2;
    const int* src = ei;
    const int* dst = ei + E;

    const int NB   = (N + B0 - 1) / B0;   // 49
    const int NPAD = NB * B0;             // 200704

    float* out_gate = (float*)d_out;
    float* out_h    = out_gate + N;
    float* out_c    = out_h + (size_t)N * H;

    // workspace layout (~31 MB)
    char* w = (char*)d_ws;
    unsigned*       psrc    = (unsigned*)w;        w += (size_t)E * 4;
    unsigned short* pdst    = (unsigned short*)w;  w += (size_t)E * 2;
    unsigned*       degp    = (unsigned*)w;        w += (size_t)P * NPAD * 4;
    float*          accp    = (float*)w;           w += (size_t)P * NPAD * 4;
    float*          y       = (float*)w;           w += (size_t)N * 4;
    float*          zv      = (float*)w;           w += (size_t)N * 4;
    float*          dinv    = (float*)w;           w += (size_t)N * 4;
    unsigned*       sizes   = (unsigned*)w;        w += MAXNB * 4;
    unsigned*       bases   = (unsigned*)w;        w += MAXNB * 4;
    unsigned*       cursors = (unsigned*)w;        w += MAXNB * 4;

    hipMemsetAsync(sizes, 0, MAXNB * sizeof(unsigned), stream);

    count_kernel  <<<512, 256, 0, stream>>>(dst, sizes, E, NB);
    prefix_kernel <<<1, 64, 0, stream>>>(sizes, bases, cursors, NB);
    scatter_kernel<<<(E + K1_EPB - 1) / K1_EPB, 256, 0, stream>>>(src, dst, cursors,
                                                                  psrc, pdst, E, NB);
    deghist_kernel<<<NB * P, 256, 0, stream>>>(pdst, sizes, bases, degp, NB, NPAD);
    node_kernel   <<<(N + 255) / 256, 256, 0, stream>>>(x, h0, c0, w_ih, w_hh, b_ih, b_hh,
                                                        gcn_w, lin_w, degp, NPAD,
                                                        out_h, out_c, y, zv, dinv, N);
    acchist_kernel<<<NB * P, 256, 0, stream>>>(psrc, pdst, sizes, bases, zv, accp, NB, NPAD);
    final_kernel  <<<(N + 255) / 256, 256, 0, stream>>>(x, accp, NPAD, y, dinv, gcn_b,
                                                        lin_w, lin_b, out_gate, N);
}